// Round 1
// 1068.321 us; speedup vs baseline: 1.0034x; 1.0034x over previous
//
#include <hip/hip_runtime.h>

// SortPool2D: x (16,224,224,256) fp32 NHWC -> out (16,112,112,256) fp32.
// For each output (b,h,w,c): sort the 2x2 spatial block {x[b,2h+dh,2w+dw,c]}
// ascending, dot with softmax(pool_weights). K_TOP=4 => all 4 sorted values.
//
// Streaming-optimal structure: one block per output row (b,h). The block's
// 256 threads sweep the 112*64 = 7168 output float4s of that row in 28
// iterations. Each iteration: 64 lanes x 16B = 1KB fully-coalesced loads of
// the four 2x2 taps; block reads input rows 2h and 2h+1 exactly once,
// perfectly sequentially (448 KB/block), writes one output row (112 KB).
// All index math is shift/and (no div/mod in the loop). Non-temporal
// loads/stores: every byte is touched exactly once, so bypass cache-line
// retention to avoid L2/L3 churn on the stream.

#define HW_IN   224
#define HW_OUT  112
#define C4      64              // 256 channels / 4 per float4
#define ROW4    (HW_IN * C4)    // float4 stride between input rows  = 14336
#define OROW4   (HW_OUT * C4)   // float4s per output row            = 7168
#define ITERS   (OROW4 / 256)   // loop trips per block              = 28

typedef float f4 __attribute__((ext_vector_type(4)));

__device__ __forceinline__ void cswap(float& a, float& b) {
    float lo = fminf(a, b);
    float hi = fmaxf(a, b);
    a = lo; b = hi;
}

__device__ __forceinline__ float sort4_dot(float v0, float v1, float v2, float v3,
                                           float w0, float w1, float w2, float w3) {
    // 5-comparator sorting network for 4 elements (ascending)
    cswap(v0, v1);
    cswap(v2, v3);
    cswap(v0, v2);
    cswap(v1, v3);
    cswap(v1, v2);
    return fmaf(w0, v0, fmaf(w1, v1, fmaf(w2, v2, w3 * v3)));
}

__global__ __launch_bounds__(256) void SortPool2D_kernel(
    const f4* __restrict__ x,
    const float* __restrict__ pw,
    f4* __restrict__ out)
{
    // block = one output row (b, h);  gridDim.x = 16*112 = 1792
    int row = blockIdx.x;
    int h   = row % HW_OUT;          // once per block, magic-mul
    int b   = row / HW_OUT;

    // softmax over the 4 pool weights (uniform; L1-hit scalar loads)
    float p0 = pw[0], p1 = pw[1], p2 = pw[2], p3 = pw[3];
    float m  = fmaxf(fmaxf(p0, p1), fmaxf(p2, p3));
    float e0 = expf(p0 - m), e1 = expf(p1 - m), e2 = expf(p2 - m), e3 = expf(p3 - m);
    float inv = 1.0f / (e0 + e1 + e2 + e3);
    e0 *= inv; e1 *= inv; e2 *= inv; e3 *= inv;

    int inBase  = (b * HW_IN + 2 * h) * ROW4;   // float4 index of input row 2h
    int outBase = row * OROW4;                  // float4 index of output row
    int t = threadIdx.x;

#pragma unroll 2
    for (int j = 0; j < ITERS; ++j) {
        int i = j * 256 + t;                    // in-row output float4 index
        int c = i & (C4 - 1);                   // channel-quad
        int w = i >> 6;                         // output pixel within row
        int o = inBase + (w << 7) + c;          // w*2*C4 + c  (all shifts)

        f4 a00 = __builtin_nontemporal_load(&x[o]);
        f4 a01 = __builtin_nontemporal_load(&x[o + C4]);
        f4 a10 = __builtin_nontemporal_load(&x[o + ROW4]);
        f4 a11 = __builtin_nontemporal_load(&x[o + ROW4 + C4]);

        f4 r;
        r.x = sort4_dot(a00.x, a01.x, a10.x, a11.x, e0, e1, e2, e3);
        r.y = sort4_dot(a00.y, a01.y, a10.y, a11.y, e0, e1, e2, e3);
        r.z = sort4_dot(a00.z, a01.z, a10.z, a11.z, e0, e1, e2, e3);
        r.w = sort4_dot(a00.w, a01.w, a10.w, a11.w, e0, e1, e2, e3);

        __builtin_nontemporal_store(r, &out[outBase + i]);
    }
}

extern "C" void kernel_launch(void* const* d_in, const int* in_sizes, int n_in,
                              void* d_out, int out_size, void* d_ws, size_t ws_size,
                              hipStream_t stream) {
    const f4*    x   = (const f4*)d_in[0];
    const float* pw  = (const float*)d_in[1];
    f4*          out = (f4*)d_out;

    int grid  = 16 * HW_OUT;   // 1792 blocks, one per output row
    int block = 256;
    SortPool2D_kernel<<<grid, block, 0, stream>>>(x, pw, out);
}